// Round 2
// baseline (589.468 us; speedup 1.0000x reference)
//
#include <hip/hip_runtime.h>
#include <cstddef>
#include <math.h>

typedef float v4 __attribute__((ext_vector_type(4)));

#define IMG_H 800
#define IMG_W 1216
#define FH 25
#define FWW 38
#define NBOX 2000
#define NKEEP 8
#define D1 100352   /* 2048*49 */
#define K1 4096
#define NSLICE 16
#define DPS (D1/NSLICE)  /* 6272 */

__device__ inline v4 ldnt4(const float* p) {
    return __builtin_nontemporal_load((const v4*)p);
}

// ---------------------------------------------------------------------------
// Kernel 1: greedy NMS (exact replica of reference loop) + ROI quantization.
// ---------------------------------------------------------------------------
__global__ __launch_bounds__(256) void nms_sel_kernel(const float* __restrict__ rois,
                                                      const float* __restrict__ scores,
                                                      int* __restrict__ roi_out) {
    __shared__ float4 s_box[NBOX];
    __shared__ float  s_fg[NBOX];
    __shared__ float  red_v[256];
    __shared__ int    red_i[256];
    __shared__ int    s_sels[NKEEP];
    const int tid = threadIdx.x;

    for (int i = tid; i < NBOX; i += 256) {
        float x1 = rois[i*4+0], y1 = rois[i*4+1], x2 = rois[i*4+2], y2 = rois[i*4+3];
        s_box[i] = make_float4(x1, y1, x2, y2);
        bool valid = (x1 >= 0.f) && (y1 >= 0.f) && (x2 <= (float)IMG_W) && (y2 <= (float)IMG_H);
        s_fg[i] = valid ? scores[i*2+1] : -INFINITY;
    }
    __syncthreads();

    for (int it = 0; it < NKEEP; ++it) {
        float bv = -INFINITY; int bi = NBOX;
        for (int i = tid; i < NBOX; i += 256) {
            float v = s_fg[i];
            if (v > bv || (v == bv && i < bi)) { bv = v; bi = i; }
        }
        red_v[tid] = bv; red_i[tid] = bi;
        __syncthreads();
        for (int off = 128; off > 0; off >>= 1) {
            if (tid < off) {
                float v = red_v[tid+off]; int ii = red_i[tid+off];
                if (v > red_v[tid] || (v == red_v[tid] && ii < red_i[tid])) {
                    red_v[tid] = v; red_i[tid] = ii;
                }
            }
            __syncthreads();
        }
        int s = red_i[0];
        if (s >= NBOX) s = 0;
        if (tid == 0) s_sels[it] = s;

        float4 bs = s_box[s];
        float a1 = (bs.z - bs.x) * (bs.w - bs.y);
        for (int i = tid; i < NBOX; i += 256) {
            float4 b = s_box[i];
            float ix1 = fmaxf(bs.x, b.x), iy1 = fmaxf(bs.y, b.y);
            float ix2 = fminf(bs.z, b.z), iy2 = fminf(bs.w, b.w);
            float inter = fmaxf(ix2 - ix1, 0.f) * fmaxf(iy2 - iy1, 0.f);
            float a2 = (b.z - b.x) * (b.w - b.y);
            float iou = inter / (a1 + a2 - inter);
            if (!(iou <= 0.6f)) s_fg[i] = -INFINITY;
        }
        __syncthreads();
    }

    if (tid < NKEEP) {
        int s = s_sels[tid];
        float4 b = s_box[s];
        int x = (int)floorf(b.x / 32.0f + 0.5f);
        int y = (int)floorf(b.y / 32.0f + 0.5f);
        int w = (int)floorf(b.z / 32.0f + 1.0f);
        int h = (int)floorf(b.w / 32.0f + 1.0f);
        bool bad = (x < 0) || (x >= FWW) || (y < 0) || (y >= FH) ||
                   (w < 1) || (x + w > FWW) || (h < 1) || (y + h > FH);
        if (bad) { x = 0; y = 0; w = FWW; h = FH; }
        roi_out[tid*4+0] = x; roi_out[tid*4+1] = y;
        roi_out[tid*4+2] = w; roi_out[tid*4+3] = h;
    }
}

// ---------------------------------------------------------------------------
// Kernel 2: adaptive 7x7 max-pool. Writes TRANSPOSED: flat_t[d*8 + r].
// idx = d*8 + r so the global write is perfectly coalesced.
// ---------------------------------------------------------------------------
__global__ __launch_bounds__(256) void roi_pool_kernel(const float* __restrict__ feat,
                                                       const int* __restrict__ roi_out,
                                                       float* __restrict__ flat_t) {
    int idx = blockIdx.x * 256 + threadIdx.x;
    if (idx >= NKEEP * D1) return;
    int r = idx & 7;
    int d = idx >> 3;
    int c = d / 49;
    int cell = d - c * 49;
    int i = cell / 7;
    int j = cell - i * 7;
    int x = roi_out[r*4+0], y = roi_out[r*4+1], w = roi_out[r*4+2], h = roi_out[r*4+3];
    int r0 = y + (i * h) / 7;
    int r1 = y + ((i + 1) * h + 6) / 7;
    int c0 = x + (j * w) / 7;
    int c1 = x + ((j + 1) * w + 6) / 7;
    const float* fc = feat + (size_t)c * (FH * FWW);
    float m = -INFINITY;
    for (int rr = r0; rr < r1; ++rr) {
        const float* fr = fc + rr * FWW;
        for (int cc2 = c0; cc2 < c1; ++cc2) m = fmaxf(m, fr[cc2]);
    }
    flat_t[idx] = m;
}

// ---------------------------------------------------------------------------
// Kernel 3: o[n][k] = b[k]  (bias init; fc1 atomically accumulates on top)
// ---------------------------------------------------------------------------
__global__ __launch_bounds__(256) void init_bias8_kernel(const float* __restrict__ b,
                                                         float* __restrict__ o, int K) {
    int i = blockIdx.x * 256 + threadIdx.x;
    if (i < NKEEP * K) o[i] = b[i & (K - 1)];
}

// ---------------------------------------------------------------------------
// Kernel 4: FC1 — the 1.64 GB w1 stream. 4 rows x 8 ROIs per thread,
// manual unroll-2 with w-prefetch (keeps next iter's HBM loads in flight
// during the FMA block), nontemporal w1 loads (don't thrash L2),
// activations read from transposed flat_t (contiguous 128B per thread).
// ---------------------------------------------------------------------------
__global__ __launch_bounds__(256, 4) void fc1_kernel(const float* __restrict__ w1,
                                                     const float* __restrict__ flat_t,
                                                     float* __restrict__ o1) {
    const int kb = blockIdx.x >> 4;       // 0..63
    const int ds = blockIdx.x & 15;       // 0..15
    const int tid = threadIdx.x;
    const int kq = tid >> 4;              // 0..15
    const int dl = tid & 15;              // 0..15
    const int k0 = kb * 64 + kq * 4;
    const int dbase = ds * DPS + dl * 4;

    const float* wp = w1 + (size_t)k0 * D1 + dbase;
    const float* ft = flat_t + (size_t)dbase * 8;

    float acc[4][8];
    #pragma unroll
    for (int a = 0; a < 4; ++a)
        #pragma unroll
        for (int n = 0; n < 8; ++n) acc[a][n] = 0.f;

    v4 wa[4], wb[4], fv[8];
    #pragma unroll
    for (int a = 0; a < 4; ++a) wa[a] = ldnt4(wp + (size_t)a * D1);

#define FC1_FMA(W)                                              \
    _Pragma("unroll")                                           \
    for (int j = 0; j < 8; ++j) {                               \
        _Pragma("unroll")                                       \
        for (int a = 0; a < 4; ++a) {                           \
            acc[a][(j&1)*4+0] += W[a][j>>1] * fv[j][0];         \
            acc[a][(j&1)*4+1] += W[a][j>>1] * fv[j][1];         \
            acc[a][(j&1)*4+2] += W[a][j>>1] * fv[j][2];         \
            acc[a][(j&1)*4+3] += W[a][j>>1] * fv[j][3];         \
        }                                                       \
    }

    for (int i2 = 0; i2 < 49; ++i2) {      // 98 half-iters of 64 columns
        const int offA = i2 * 128;
        const int offB = offA + 64;
        const int offN = (i2 < 48) ? (offA + 128) : 0;  // safe dummy on last

        #pragma unroll
        for (int a = 0; a < 4; ++a) wb[a] = ldnt4(wp + (size_t)a * D1 + offB);
        {
            const v4* fp = (const v4*)(ft + (size_t)offA * 8);
            #pragma unroll
            for (int j = 0; j < 8; ++j) fv[j] = fp[j];
        }
        FC1_FMA(wa);

        #pragma unroll
        for (int a = 0; a < 4; ++a) wa[a] = ldnt4(wp + (size_t)a * D1 + offN);
        {
            const v4* fp = (const v4*)(ft + (size_t)offB * 8);
            #pragma unroll
            for (int j = 0; j < 8; ++j) fv[j] = fp[j];
        }
        FC1_FMA(wb);
    }

    // reduce across the 16 d-lanes, then atomic into o1
    #pragma unroll
    for (int a = 0; a < 4; ++a) {
        #pragma unroll
        for (int n = 0; n < 8; ++n) {
            float v = acc[a][n];
            v += __shfl_xor(v, 1);
            v += __shfl_xor(v, 2);
            v += __shfl_xor(v, 4);
            v += __shfl_xor(v, 8);
            if (dl == 0) atomicAdd(&o1[n * K1 + k0 + a], v);
        }
    }
}

// ---------------------------------------------------------------------------
// Kernel 5: FC2 (8x4096)@(4096x4096). One wave per output row k.
// ---------------------------------------------------------------------------
__global__ __launch_bounds__(256) void fc2_kernel(const float* __restrict__ w2,
                                                  const float* __restrict__ o1,
                                                  const float* __restrict__ b2,
                                                  float* __restrict__ o2) {
    int gw   = (blockIdx.x * 256 + threadIdx.x) >> 6;
    int lane = threadIdx.x & 63;
    if (gw >= K1) return;
    const float* wr = w2 + (size_t)gw * K1;
    const v4* fo = (const v4*)o1;
    float acc[8];
    #pragma unroll
    for (int n = 0; n < 8; ++n) acc[n] = 0.f;
    for (int itn = 0; itn < K1 / 256; ++itn) {   // 16
        v4 wv = ldnt4(wr + (itn * 64 + lane) * 4);
        #pragma unroll
        for (int n = 0; n < 8; ++n) {
            v4 f = fo[n * (K1/4) + itn * 64 + lane];
            acc[n] += wv[0]*f[0] + wv[1]*f[1] + wv[2]*f[2] + wv[3]*f[3];
        }
    }
    #pragma unroll
    for (int n = 0; n < 8; ++n) {
        float v = acc[n];
        #pragma unroll
        for (int m = 32; m >= 1; m >>= 1) v += __shfl_xor(v, m);
        if (lane == 0) o2[n * K1 + gw] = v + b2[gw];
    }
}

// ---------------------------------------------------------------------------
// Kernel 6: heads. k<81 -> wc/bc, else wl/bl. out (8,405) row-major.
// ---------------------------------------------------------------------------
__global__ __launch_bounds__(256) void fc3_kernel(const float* __restrict__ wc,
                                                  const float* __restrict__ bc,
                                                  const float* __restrict__ wl,
                                                  const float* __restrict__ bl,
                                                  const float* __restrict__ o2,
                                                  float* __restrict__ out) {
    int gw   = (blockIdx.x * 256 + threadIdx.x) >> 6;
    int lane = threadIdx.x & 63;
    if (gw >= 405) return;
    const float* wrow; float bias;
    if (gw < 81) { wrow = wc + (size_t)gw * K1;        bias = bc[gw]; }
    else         { wrow = wl + (size_t)(gw - 81) * K1; bias = bl[gw - 81]; }
    const v4* fo = (const v4*)o2;
    float acc[8];
    #pragma unroll
    for (int n = 0; n < 8; ++n) acc[n] = 0.f;
    for (int itn = 0; itn < K1 / 256; ++itn) {
        v4 wv = ldnt4(wrow + (itn * 64 + lane) * 4);
        #pragma unroll
        for (int n = 0; n < 8; ++n) {
            v4 f = fo[n * (K1/4) + itn * 64 + lane];
            acc[n] += wv[0]*f[0] + wv[1]*f[1] + wv[2]*f[2] + wv[3]*f[3];
        }
    }
    #pragma unroll
    for (int n = 0; n < 8; ++n) {
        float v = acc[n];
        #pragma unroll
        for (int m = 32; m >= 1; m >>= 1) v += __shfl_xor(v, m);
        if (lane == 0) out[n * 405 + gw] = v + bias;
    }
}

// ---------------------------------------------------------------------------
extern "C" void kernel_launch(void* const* d_in, const int* in_sizes, int n_in,
                              void* d_out, int out_size, void* d_ws, size_t ws_size,
                              hipStream_t stream) {
    const float* feat   = (const float*)d_in[0];
    const float* rois   = (const float*)d_in[1];
    const float* scores = (const float*)d_in[2];
    const float* w1     = (const float*)d_in[3];
    const float* b1     = (const float*)d_in[4];
    const float* w2     = (const float*)d_in[5];
    const float* b2     = (const float*)d_in[6];
    const float* wc     = (const float*)d_in[7];
    const float* bc     = (const float*)d_in[8];
    const float* wl     = (const float*)d_in[9];
    const float* bl     = (const float*)d_in[10];
    float* out = (float*)d_out;

    // workspace layout (floats): [0..255] roi ints, then flat_t, o1, o2
    int*   roi_out = (int*)d_ws;
    float* flat_t  = (float*)d_ws + 256;
    float* o1      = flat_t + (size_t)NKEEP * D1;
    float* o2      = o1 + NKEEP * K1;

    nms_sel_kernel<<<1, 256, 0, stream>>>(rois, scores, roi_out);
    roi_pool_kernel<<<(NKEEP * D1 + 255) / 256, 256, 0, stream>>>(feat, roi_out, flat_t);
    init_bias8_kernel<<<(NKEEP * K1 + 255) / 256, 256, 0, stream>>>(b1, o1, K1);
    fc1_kernel<<<64 * NSLICE, 256, 0, stream>>>(w1, flat_t, o1);
    fc2_kernel<<<K1 / 4, 256, 0, stream>>>(w2, o1, b2, o2);
    fc3_kernel<<<(405 * 64 + 255) / 256, 256, 0, stream>>>(wc, bc, wl, bl, o2, out);
}

// Round 3
// 495.842 us; speedup vs baseline: 1.1888x; 1.1888x over previous
//
#include <hip/hip_runtime.h>
#include <cstddef>
#include <math.h>

typedef float v4 __attribute__((ext_vector_type(4)));

#define IMG_H 800
#define IMG_W 1216
#define FH 25
#define FWW 38
#define NBOX 2000
#define NKEEP 8
#define D1 100352   /* 2048*49 */
#define K1 4096
#define NSLICE 98
#define DPS 1024    /* D1/NSLICE */

// ---------------------------------------------------------------------------
// Kernel 1: greedy NMS (exact replica of reference loop) + ROI quantization.
// ---------------------------------------------------------------------------
__global__ __launch_bounds__(256) void nms_sel_kernel(const float* __restrict__ rois,
                                                      const float* __restrict__ scores,
                                                      int* __restrict__ roi_out) {
    __shared__ float4 s_box[NBOX];
    __shared__ float  s_fg[NBOX];
    __shared__ float  red_v[256];
    __shared__ int    red_i[256];
    __shared__ int    s_sels[NKEEP];
    const int tid = threadIdx.x;

    for (int i = tid; i < NBOX; i += 256) {
        float x1 = rois[i*4+0], y1 = rois[i*4+1], x2 = rois[i*4+2], y2 = rois[i*4+3];
        s_box[i] = make_float4(x1, y1, x2, y2);
        bool valid = (x1 >= 0.f) && (y1 >= 0.f) && (x2 <= (float)IMG_W) && (y2 <= (float)IMG_H);
        s_fg[i] = valid ? scores[i*2+1] : -INFINITY;
    }
    __syncthreads();

    for (int it = 0; it < NKEEP; ++it) {
        float bv = -INFINITY; int bi = NBOX;
        for (int i = tid; i < NBOX; i += 256) {
            float v = s_fg[i];
            if (v > bv || (v == bv && i < bi)) { bv = v; bi = i; }
        }
        red_v[tid] = bv; red_i[tid] = bi;
        __syncthreads();
        for (int off = 128; off > 0; off >>= 1) {
            if (tid < off) {
                float v = red_v[tid+off]; int ii = red_i[tid+off];
                if (v > red_v[tid] || (v == red_v[tid] && ii < red_i[tid])) {
                    red_v[tid] = v; red_i[tid] = ii;
                }
            }
            __syncthreads();
        }
        int s = red_i[0];
        if (s >= NBOX) s = 0;
        if (tid == 0) s_sels[it] = s;

        float4 bs = s_box[s];
        float a1 = (bs.z - bs.x) * (bs.w - bs.y);
        for (int i = tid; i < NBOX; i += 256) {
            float4 b = s_box[i];
            float ix1 = fmaxf(bs.x, b.x), iy1 = fmaxf(bs.y, b.y);
            float ix2 = fminf(bs.z, b.z), iy2 = fminf(bs.w, b.w);
            float inter = fmaxf(ix2 - ix1, 0.f) * fmaxf(iy2 - iy1, 0.f);
            float a2 = (b.z - b.x) * (b.w - b.y);
            float iou = inter / (a1 + a2 - inter);
            if (!(iou <= 0.6f)) s_fg[i] = -INFINITY;
        }
        __syncthreads();
    }

    if (tid < NKEEP) {
        int s = s_sels[tid];
        float4 b = s_box[s];
        int x = (int)floorf(b.x / 32.0f + 0.5f);
        int y = (int)floorf(b.y / 32.0f + 0.5f);
        int w = (int)floorf(b.z / 32.0f + 1.0f);
        int h = (int)floorf(b.w / 32.0f + 1.0f);
        bool bad = (x < 0) || (x >= FWW) || (y < 0) || (y >= FH) ||
                   (w < 1) || (x + w > FWW) || (h < 1) || (y + h > FH);
        if (bad) { x = 0; y = 0; w = FWW; h = FH; }
        roi_out[tid*4+0] = x; roi_out[tid*4+1] = y;
        roi_out[tid*4+2] = w; roi_out[tid*4+3] = h;
    }
}

// ---------------------------------------------------------------------------
// Kernel 2: adaptive 7x7 max-pool. pooled flat: idx = r*D1 + c*49 + i*7 + j
// ---------------------------------------------------------------------------
__global__ __launch_bounds__(256) void roi_pool_kernel(const float* __restrict__ feat,
                                                       const int* __restrict__ roi_out,
                                                       float* __restrict__ pooled) {
    int idx = blockIdx.x * 256 + threadIdx.x;
    if (idx >= NKEEP * D1) return;
    int r    = idx / D1;
    int rem  = idx - r * D1;
    int c    = rem / 49;
    int cell = rem - c * 49;
    int i = cell / 7;
    int j = cell - i * 7;
    int x = roi_out[r*4+0], y = roi_out[r*4+1], w = roi_out[r*4+2], h = roi_out[r*4+3];
    int r0 = y + (i * h) / 7;
    int r1 = y + ((i + 1) * h + 6) / 7;
    int c0 = x + (j * w) / 7;
    int c1 = x + ((j + 1) * w + 6) / 7;
    const float* fc = feat + (size_t)c * (FH * FWW);
    float m = -INFINITY;
    for (int rr = r0; rr < r1; ++rr) {
        const float* fr = fc + rr * FWW;
        for (int cc2 = c0; cc2 < c1; ++cc2) m = fmaxf(m, fr[cc2]);
    }
    pooled[idx] = m;
}

// ---------------------------------------------------------------------------
// Kernel 3: o[n][k] = b[k]  (bias init; fc1 atomically accumulates on top)
// ---------------------------------------------------------------------------
__global__ __launch_bounds__(256) void init_bias8_kernel(const float* __restrict__ b,
                                                         float* __restrict__ o, int K) {
    int i = blockIdx.x * 256 + threadIdx.x;
    if (i < NKEEP * K) o[i] = b[i & (K - 1)];
}

// ---------------------------------------------------------------------------
// Kernel 4: FC1 — the 1.64 GB w1 stream, activations staged in LDS.
// Grid = 64 k-blocks x 98 d-slices. Block stages its 8x1024 activation
// slice (32 KB LDS) once; main loop is pure w1 HBM stream + ds_read_b128
// (2-way bank aliasing only = free) + 128 FMAs. 5 blocks/CU resident.
// ---------------------------------------------------------------------------
__global__ __launch_bounds__(256) void fc1_kernel(const float* __restrict__ w1,
                                                  const float* __restrict__ flat,
                                                  float* __restrict__ o1) {
    __shared__ float s_f[NKEEP][DPS];   // 32 KB

    const int bid = blockIdx.x;
    const int kb = bid / NSLICE;          // 0..63
    const int ds = bid - kb * NSLICE;     // 0..97
    const int tid = threadIdx.x;
    const int kq = tid >> 4;              // 0..15
    const int dl = tid & 15;              // 0..15
    const int k0 = kb * 64 + kq * 4;
    const int dbase = ds * DPS;

    // stage activations: 8 x 1024 floats, fully coalesced
    {
        const v4* src = (const v4*)(flat);
        v4* dst = (v4*)&s_f[0][0];
        #pragma unroll
        for (int it = 0; it < (NKEEP * DPS / 4) / 256; ++it) {  // 8 iters
            int l = it * 256 + tid;
            int n  = l >> 8;          // /(DPS/4)
            int d4 = l & 255;
            dst[l] = src[(size_t)n * (D1 / 4) + (dbase >> 2) + d4];
        }
    }
    __syncthreads();

    const float* wp = w1 + (size_t)k0 * D1 + dbase + dl * 4;

    float acc[4][8];
    #pragma unroll
    for (int a = 0; a < 4; ++a)
        #pragma unroll
        for (int n = 0; n < 8; ++n) acc[a][n] = 0.f;

    for (int itn = 0; itn < DPS / 64; ++itn) {   // 16 iters of 64 cols
        const int off = itn * 64;
        v4 wv0 = *(const v4*)(wp + off);
        v4 wv1 = *(const v4*)(wp + (size_t)D1 + off);
        v4 wv2 = *(const v4*)(wp + (size_t)2 * D1 + off);
        v4 wv3 = *(const v4*)(wp + (size_t)3 * D1 + off);
        #pragma unroll
        for (int n = 0; n < 8; ++n) {
            v4 f = *(const v4*)&s_f[n][dl * 4 + off];
            acc[0][n] += wv0[0]*f[0] + wv0[1]*f[1] + wv0[2]*f[2] + wv0[3]*f[3];
            acc[1][n] += wv1[0]*f[0] + wv1[1]*f[1] + wv1[2]*f[2] + wv1[3]*f[3];
            acc[2][n] += wv2[0]*f[0] + wv2[1]*f[1] + wv2[2]*f[2] + wv2[3]*f[3];
            acc[3][n] += wv3[0]*f[0] + wv3[1]*f[1] + wv3[2]*f[2] + wv3[3]*f[3];
        }
    }

    // reduce across the 16 d-lanes, then atomic into o1
    #pragma unroll
    for (int a = 0; a < 4; ++a) {
        #pragma unroll
        for (int n = 0; n < 8; ++n) {
            float v = acc[a][n];
            v += __shfl_xor(v, 1);
            v += __shfl_xor(v, 2);
            v += __shfl_xor(v, 4);
            v += __shfl_xor(v, 8);
            if (dl == 0) atomicAdd(&o1[n * K1 + k0 + a], v);
        }
    }
}

// ---------------------------------------------------------------------------
// Kernel 5: FC2 (8x4096)@(4096x4096). One wave per output row k.
// ---------------------------------------------------------------------------
__global__ __launch_bounds__(256) void fc2_kernel(const float* __restrict__ w2,
                                                  const float* __restrict__ o1,
                                                  const float* __restrict__ b2,
                                                  float* __restrict__ o2) {
    int gw   = (blockIdx.x * 256 + threadIdx.x) >> 6;
    int lane = threadIdx.x & 63;
    if (gw >= K1) return;
    const float4* wr = (const float4*)(w2 + (size_t)gw * K1);
    const float4* fo = (const float4*)o1;
    float acc[8];
    #pragma unroll
    for (int n = 0; n < 8; ++n) acc[n] = 0.f;
    for (int itn = 0; itn < K1 / 256; ++itn) {   // 16
        float4 wv = wr[itn * 64 + lane];
        #pragma unroll
        for (int n = 0; n < 8; ++n) {
            float4 f = fo[n * (K1/4) + itn * 64 + lane];
            acc[n] += wv.x*f.x + wv.y*f.y + wv.z*f.z + wv.w*f.w;
        }
    }
    #pragma unroll
    for (int n = 0; n < 8; ++n) {
        float v = acc[n];
        #pragma unroll
        for (int m = 32; m >= 1; m >>= 1) v += __shfl_xor(v, m);
        if (lane == 0) o2[n * K1 + gw] = v + b2[gw];
    }
}

// ---------------------------------------------------------------------------
// Kernel 6: heads. k<81 -> wc/bc, else wl/bl. out (8,405) row-major.
// ---------------------------------------------------------------------------
__global__ __launch_bounds__(256) void fc3_kernel(const float* __restrict__ wc,
                                                  const float* __restrict__ bc,
                                                  const float* __restrict__ wl,
                                                  const float* __restrict__ bl,
                                                  const float* __restrict__ o2,
                                                  float* __restrict__ out) {
    int gw   = (blockIdx.x * 256 + threadIdx.x) >> 6;
    int lane = threadIdx.x & 63;
    if (gw >= 405) return;
    const float* wrow; float bias;
    if (gw < 81) { wrow = wc + (size_t)gw * K1;        bias = bc[gw]; }
    else         { wrow = wl + (size_t)(gw - 81) * K1; bias = bl[gw - 81]; }
    const float4* wr = (const float4*)wrow;
    const float4* fo = (const float4*)o2;
    float acc[8];
    #pragma unroll
    for (int n = 0; n < 8; ++n) acc[n] = 0.f;
    for (int itn = 0; itn < K1 / 256; ++itn) {
        float4 wv = wr[itn * 64 + lane];
        #pragma unroll
        for (int n = 0; n < 8; ++n) {
            float4 f = fo[n * (K1/4) + itn * 64 + lane];
            acc[n] += wv.x*f.x + wv.y*f.y + wv.z*f.z + wv.w*f.w;
        }
    }
    #pragma unroll
    for (int n = 0; n < 8; ++n) {
        float v = acc[n];
        #pragma unroll
        for (int m = 32; m >= 1; m >>= 1) v += __shfl_xor(v, m);
        if (lane == 0) out[n * 405 + gw] = v + bias;
    }
}

// ---------------------------------------------------------------------------
extern "C" void kernel_launch(void* const* d_in, const int* in_sizes, int n_in,
                              void* d_out, int out_size, void* d_ws, size_t ws_size,
                              hipStream_t stream) {
    const float* feat   = (const float*)d_in[0];
    const float* rois   = (const float*)d_in[1];
    const float* scores = (const float*)d_in[2];
    const float* w1     = (const float*)d_in[3];
    const float* b1     = (const float*)d_in[4];
    const float* w2     = (const float*)d_in[5];
    const float* b2     = (const float*)d_in[6];
    const float* wc     = (const float*)d_in[7];
    const float* bc     = (const float*)d_in[8];
    const float* wl     = (const float*)d_in[9];
    const float* bl     = (const float*)d_in[10];
    float* out = (float*)d_out;

    // workspace layout (floats): [0..255] roi ints, then pooled, o1, o2
    int*   roi_out = (int*)d_ws;
    float* pooled  = (float*)d_ws + 256;
    float* o1      = pooled + (size_t)NKEEP * D1;
    float* o2      = o1 + NKEEP * K1;

    nms_sel_kernel<<<1, 256, 0, stream>>>(rois, scores, roi_out);
    roi_pool_kernel<<<(NKEEP * D1 + 255) / 256, 256, 0, stream>>>(feat, roi_out, pooled);
    init_bias8_kernel<<<(NKEEP * K1 + 255) / 256, 256, 0, stream>>>(b1, o1, K1);
    fc1_kernel<<<64 * NSLICE, 256, 0, stream>>>(w1, pooled, o1);
    fc2_kernel<<<K1 / 4, 256, 0, stream>>>(w2, o1, b2, o2);
    fc3_kernel<<<(405 * 64 + 255) / 256, 256, 0, stream>>>(wc, bc, wl, bl, o2, out);
}

// Round 4
// 475.358 us; speedup vs baseline: 1.2401x; 1.0431x over previous
//
#include <hip/hip_runtime.h>
#include <cstddef>
#include <math.h>

typedef float v4 __attribute__((ext_vector_type(4)));

#define IMG_H 800
#define IMG_W 1216
#define FH 25
#define FWW 38
#define NBOX 2000
#define NKEEP 8
#define D1 100352   /* 2048*49 */
#define K1 4096

// ---------------------------------------------------------------------------
// Kernel 1: greedy NMS (exact replica of reference loop) + ROI quantization.
// ---------------------------------------------------------------------------
__global__ __launch_bounds__(256) void nms_sel_kernel(const float* __restrict__ rois,
                                                      const float* __restrict__ scores,
                                                      int* __restrict__ roi_out) {
    __shared__ float4 s_box[NBOX];
    __shared__ float  s_fg[NBOX];
    __shared__ float  red_v[256];
    __shared__ int    red_i[256];
    __shared__ int    s_sels[NKEEP];
    const int tid = threadIdx.x;

    for (int i = tid; i < NBOX; i += 256) {
        float x1 = rois[i*4+0], y1 = rois[i*4+1], x2 = rois[i*4+2], y2 = rois[i*4+3];
        s_box[i] = make_float4(x1, y1, x2, y2);
        bool valid = (x1 >= 0.f) && (y1 >= 0.f) && (x2 <= (float)IMG_W) && (y2 <= (float)IMG_H);
        s_fg[i] = valid ? scores[i*2+1] : -INFINITY;
    }
    __syncthreads();

    for (int it = 0; it < NKEEP; ++it) {
        float bv = -INFINITY; int bi = NBOX;
        for (int i = tid; i < NBOX; i += 256) {
            float v = s_fg[i];
            if (v > bv || (v == bv && i < bi)) { bv = v; bi = i; }
        }
        red_v[tid] = bv; red_i[tid] = bi;
        __syncthreads();
        for (int off = 128; off > 0; off >>= 1) {
            if (tid < off) {
                float v = red_v[tid+off]; int ii = red_i[tid+off];
                if (v > red_v[tid] || (v == red_v[tid] && ii < red_i[tid])) {
                    red_v[tid] = v; red_i[tid] = ii;
                }
            }
            __syncthreads();
        }
        int s = red_i[0];
        if (s >= NBOX) s = 0;
        if (tid == 0) s_sels[it] = s;

        float4 bs = s_box[s];
        float a1 = (bs.z - bs.x) * (bs.w - bs.y);
        for (int i = tid; i < NBOX; i += 256) {
            float4 b = s_box[i];
            float ix1 = fmaxf(bs.x, b.x), iy1 = fmaxf(bs.y, b.y);
            float ix2 = fminf(bs.z, b.z), iy2 = fminf(bs.w, b.w);
            float inter = fmaxf(ix2 - ix1, 0.f) * fmaxf(iy2 - iy1, 0.f);
            float a2 = (b.z - b.x) * (b.w - b.y);
            float iou = inter / (a1 + a2 - inter);
            if (!(iou <= 0.6f)) s_fg[i] = -INFINITY;
        }
        __syncthreads();
    }

    if (tid < NKEEP) {
        int s = s_sels[tid];
        float4 b = s_box[s];
        int x = (int)floorf(b.x / 32.0f + 0.5f);
        int y = (int)floorf(b.y / 32.0f + 0.5f);
        int w = (int)floorf(b.z / 32.0f + 1.0f);
        int h = (int)floorf(b.w / 32.0f + 1.0f);
        bool bad = (x < 0) || (x >= FWW) || (y < 0) || (y >= FH) ||
                   (w < 1) || (x + w > FWW) || (h < 1) || (y + h > FH);
        if (bad) { x = 0; y = 0; w = FWW; h = FH; }
        roi_out[tid*4+0] = x; roi_out[tid*4+1] = y;
        roi_out[tid*4+2] = w; roi_out[tid*4+3] = h;
    }
}

// ---------------------------------------------------------------------------
// Kernel 2: adaptive 7x7 max-pool. pooled flat: idx = r*D1 + c*49 + i*7 + j
// ---------------------------------------------------------------------------
__global__ __launch_bounds__(256) void roi_pool_kernel(const float* __restrict__ feat,
                                                       const int* __restrict__ roi_out,
                                                       float* __restrict__ pooled) {
    int idx = blockIdx.x * 256 + threadIdx.x;
    if (idx >= NKEEP * D1) return;
    int r    = idx / D1;
    int rem  = idx - r * D1;
    int c    = rem / 49;
    int cell = rem - c * 49;
    int i = cell / 7;
    int j = cell - i * 7;
    int x = roi_out[r*4+0], y = roi_out[r*4+1], w = roi_out[r*4+2], h = roi_out[r*4+3];
    int r0 = y + (i * h) / 7;
    int r1 = y + ((i + 1) * h + 6) / 7;
    int c0 = x + (j * w) / 7;
    int c1 = x + ((j + 1) * w + 6) / 7;
    const float* fc = feat + (size_t)c * (FH * FWW);
    float m = -INFINITY;
    for (int rr = r0; rr < r1; ++rr) {
        const float* fr = fc + rr * FWW;
        for (int cc2 = c0; cc2 < c1; ++cc2) m = fmaxf(m, fr[cc2]);
    }
    pooled[idx] = m;
}

// ---------------------------------------------------------------------------
// Kernel 3: FC1 — block owns 4 FULL w1 rows (4 x 401 KB sequential streams).
// Per wave-instruction: contiguous 1 KB of one row -> DRAM row-buffer hits.
// 1024 blocks x 4 rows = 4096 device-wide streams (~HBM bank count).
// Block-reduce (shfl + LDS) writes o1 with bias directly — no atomics,
// no init kernel.
// ---------------------------------------------------------------------------
__global__ __launch_bounds__(256) void fc1_kernel(const float* __restrict__ w1,
                                                  const float* __restrict__ flat,
                                                  const float* __restrict__ b1,
                                                  float* __restrict__ o1) {
    const int b = blockIdx.x;           // 0..1023 -> rows 4b..4b+3
    const int t = threadIdx.x;
    const float* wp = w1 + (size_t)(4 * b) * D1 + t * 4;
    const float* fp = flat + t * 4;

    float acc[4][8];
    #pragma unroll
    for (int a = 0; a < 4; ++a)
        #pragma unroll
        for (int n = 0; n < 8; ++n) acc[a][n] = 0.f;

    for (int i = 0; i < 98; ++i) {       // 1024-col stripes
        const int off = i * 1024;
        v4 wv0 = *(const v4*)(wp + off);
        v4 wv1 = *(const v4*)(wp + D1 + off);
        v4 wv2 = *(const v4*)(wp + 2 * D1 + off);
        v4 wv3 = *(const v4*)(wp + 3 * D1 + off);
        #pragma unroll
        for (int n = 0; n < 8; ++n) {
            v4 f = *(const v4*)(fp + n * D1 + off);
            acc[0][n] += wv0[0]*f[0] + wv0[1]*f[1] + wv0[2]*f[2] + wv0[3]*f[3];
            acc[1][n] += wv1[0]*f[0] + wv1[1]*f[1] + wv1[2]*f[2] + wv1[3]*f[3];
            acc[2][n] += wv2[0]*f[0] + wv2[1]*f[1] + wv2[2]*f[2] + wv2[3]*f[3];
            acc[3][n] += wv3[0]*f[0] + wv3[1]*f[1] + wv3[2]*f[2] + wv3[3]*f[3];
        }
    }

    // block reduction: wave shfl-reduce then cross-wave LDS sum
    __shared__ float red[4][32];
    const int lane = t & 63;
    const int wid  = t >> 6;
    #pragma unroll
    for (int a = 0; a < 4; ++a) {
        #pragma unroll
        for (int n = 0; n < 8; ++n) {
            float v = acc[a][n];
            v += __shfl_xor(v, 1);
            v += __shfl_xor(v, 2);
            v += __shfl_xor(v, 4);
            v += __shfl_xor(v, 8);
            v += __shfl_xor(v, 16);
            v += __shfl_xor(v, 32);
            if (lane == 0) red[wid][a * 8 + n] = v;
        }
    }
    __syncthreads();
    if (t < 32) {
        float v = red[0][t] + red[1][t] + red[2][t] + red[3][t];
        int a = t >> 3;
        int n = t & 7;
        int k = 4 * b + a;
        o1[n * K1 + k] = v + b1[k];
    }
}

// ---------------------------------------------------------------------------
// Kernel 4: FC2 (8x4096)@(4096x4096). One wave per output row k.
// ---------------------------------------------------------------------------
__global__ __launch_bounds__(256) void fc2_kernel(const float* __restrict__ w2,
                                                  const float* __restrict__ o1,
                                                  const float* __restrict__ b2,
                                                  float* __restrict__ o2) {
    int gw   = (blockIdx.x * 256 + threadIdx.x) >> 6;
    int lane = threadIdx.x & 63;
    if (gw >= K1) return;
    const float4* wr = (const float4*)(w2 + (size_t)gw * K1);
    const float4* fo = (const float4*)o1;
    float acc[8];
    #pragma unroll
    for (int n = 0; n < 8; ++n) acc[n] = 0.f;
    for (int itn = 0; itn < K1 / 256; ++itn) {   // 16
        float4 wv = wr[itn * 64 + lane];
        #pragma unroll
        for (int n = 0; n < 8; ++n) {
            float4 f = fo[n * (K1/4) + itn * 64 + lane];
            acc[n] += wv.x*f.x + wv.y*f.y + wv.z*f.z + wv.w*f.w;
        }
    }
    #pragma unroll
    for (int n = 0; n < 8; ++n) {
        float v = acc[n];
        #pragma unroll
        for (int m = 32; m >= 1; m >>= 1) v += __shfl_xor(v, m);
        if (lane == 0) o2[n * K1 + gw] = v + b2[gw];
    }
}

// ---------------------------------------------------------------------------
// Kernel 5: heads. k<81 -> wc/bc, else wl/bl. out (8,405) row-major.
// ---------------------------------------------------------------------------
__global__ __launch_bounds__(256) void fc3_kernel(const float* __restrict__ wc,
                                                  const float* __restrict__ bc,
                                                  const float* __restrict__ wl,
                                                  const float* __restrict__ bl,
                                                  const float* __restrict__ o2,
                                                  float* __restrict__ out) {
    int gw   = (blockIdx.x * 256 + threadIdx.x) >> 6;
    int lane = threadIdx.x & 63;
    if (gw >= 405) return;
    const float* wrow; float bias;
    if (gw < 81) { wrow = wc + (size_t)gw * K1;        bias = bc[gw]; }
    else         { wrow = wl + (size_t)(gw - 81) * K1; bias = bl[gw - 81]; }
    const float4* wr = (const float4*)wrow;
    const float4* fo = (const float4*)o2;
    float acc[8];
    #pragma unroll
    for (int n = 0; n < 8; ++n) acc[n] = 0.f;
    for (int itn = 0; itn < K1 / 256; ++itn) {
        float4 wv = wr[itn * 64 + lane];
        #pragma unroll
        for (int n = 0; n < 8; ++n) {
            float4 f = fo[n * (K1/4) + itn * 64 + lane];
            acc[n] += wv.x*f.x + wv.y*f.y + wv.z*f.z + wv.w*f.w;
        }
    }
    #pragma unroll
    for (int n = 0; n < 8; ++n) {
        float v = acc[n];
        #pragma unroll
        for (int m = 32; m >= 1; m >>= 1) v += __shfl_xor(v, m);
        if (lane == 0) out[n * 405 + gw] = v + bias;
    }
}

// ---------------------------------------------------------------------------
extern "C" void kernel_launch(void* const* d_in, const int* in_sizes, int n_in,
                              void* d_out, int out_size, void* d_ws, size_t ws_size,
                              hipStream_t stream) {
    const float* feat   = (const float*)d_in[0];
    const float* rois   = (const float*)d_in[1];
    const float* scores = (const float*)d_in[2];
    const float* w1     = (const float*)d_in[3];
    const float* b1     = (const float*)d_in[4];
    const float* w2     = (const float*)d_in[5];
    const float* b2     = (const float*)d_in[6];
    const float* wc     = (const float*)d_in[7];
    const float* bc     = (const float*)d_in[8];
    const float* wl     = (const float*)d_in[9];
    const float* bl     = (const float*)d_in[10];
    float* out = (float*)d_out;

    // workspace layout (floats): [0..255] roi ints, then pooled, o1, o2
    int*   roi_out = (int*)d_ws;
    float* pooled  = (float*)d_ws + 256;
    float* o1      = pooled + (size_t)NKEEP * D1;
    float* o2      = o1 + NKEEP * K1;

    nms_sel_kernel<<<1, 256, 0, stream>>>(rois, scores, roi_out);
    roi_pool_kernel<<<(NKEEP * D1 + 255) / 256, 256, 0, stream>>>(feat, roi_out, pooled);
    fc1_kernel<<<K1 / 4, 256, 0, stream>>>(w1, pooled, b1, o1);
    fc2_kernel<<<K1 / 4, 256, 0, stream>>>(w2, o1, b2, o2);
    fc3_kernel<<<(405 * 64 + 255) / 256, 256, 0, stream>>>(wc, bc, wl, bl, o2, out);
}

// Round 5
// 405.186 us; speedup vs baseline: 1.4548x; 1.1732x over previous
//
#include <hip/hip_runtime.h>
#include <cstddef>
#include <math.h>

typedef float v4 __attribute__((ext_vector_type(4)));

#define IMG_H 800
#define IMG_W 1216
#define FH 25
#define FWW 38
#define NBOX 2000
#define NKEEP 8
#define D1 100352   /* 2048*49 */
#define K1 4096
#define NSLICE 16
#define DPS (D1/NSLICE)  /* 6272 */

// ---------------------------------------------------------------------------
// Kernel 1: greedy NMS (exact replica of reference loop) + ROI quantization.
// ---------------------------------------------------------------------------
__global__ __launch_bounds__(256) void nms_sel_kernel(const float* __restrict__ rois,
                                                      const float* __restrict__ scores,
                                                      int* __restrict__ roi_out) {
    __shared__ float4 s_box[NBOX];
    __shared__ float  s_fg[NBOX];
    __shared__ float  red_v[256];
    __shared__ int    red_i[256];
    __shared__ int    s_sels[NKEEP];
    const int tid = threadIdx.x;

    for (int i = tid; i < NBOX; i += 256) {
        float x1 = rois[i*4+0], y1 = rois[i*4+1], x2 = rois[i*4+2], y2 = rois[i*4+3];
        s_box[i] = make_float4(x1, y1, x2, y2);
        bool valid = (x1 >= 0.f) && (y1 >= 0.f) && (x2 <= (float)IMG_W) && (y2 <= (float)IMG_H);
        s_fg[i] = valid ? scores[i*2+1] : -INFINITY;
    }
    __syncthreads();

    for (int it = 0; it < NKEEP; ++it) {
        float bv = -INFINITY; int bi = NBOX;
        for (int i = tid; i < NBOX; i += 256) {
            float v = s_fg[i];
            if (v > bv || (v == bv && i < bi)) { bv = v; bi = i; }
        }
        red_v[tid] = bv; red_i[tid] = bi;
        __syncthreads();
        for (int off = 128; off > 0; off >>= 1) {
            if (tid < off) {
                float v = red_v[tid+off]; int ii = red_i[tid+off];
                if (v > red_v[tid] || (v == red_v[tid] && ii < red_i[tid])) {
                    red_v[tid] = v; red_i[tid] = ii;
                }
            }
            __syncthreads();
        }
        int s = red_i[0];
        if (s >= NBOX) s = 0;
        if (tid == 0) s_sels[it] = s;

        float4 bs = s_box[s];
        float a1 = (bs.z - bs.x) * (bs.w - bs.y);
        for (int i = tid; i < NBOX; i += 256) {
            float4 b = s_box[i];
            float ix1 = fmaxf(bs.x, b.x), iy1 = fmaxf(bs.y, b.y);
            float ix2 = fminf(bs.z, b.z), iy2 = fminf(bs.w, b.w);
            float inter = fmaxf(ix2 - ix1, 0.f) * fmaxf(iy2 - iy1, 0.f);
            float a2 = (b.z - b.x) * (b.w - b.y);
            float iou = inter / (a1 + a2 - inter);
            if (!(iou <= 0.6f)) s_fg[i] = -INFINITY;
        }
        __syncthreads();
    }

    if (tid < NKEEP) {
        int s = s_sels[tid];
        float4 b = s_box[s];
        int x = (int)floorf(b.x / 32.0f + 0.5f);
        int y = (int)floorf(b.y / 32.0f + 0.5f);
        int w = (int)floorf(b.z / 32.0f + 1.0f);
        int h = (int)floorf(b.w / 32.0f + 1.0f);
        bool bad = (x < 0) || (x >= FWW) || (y < 0) || (y >= FH) ||
                   (w < 1) || (x + w > FWW) || (h < 1) || (y + h > FH);
        if (bad) { x = 0; y = 0; w = FWW; h = FH; }
        roi_out[tid*4+0] = x; roi_out[tid*4+1] = y;
        roi_out[tid*4+2] = w; roi_out[tid*4+3] = h;
    }
}

// ---------------------------------------------------------------------------
// Kernel 2: adaptive 7x7 max-pool. pooled flat: idx = r*D1 + c*49 + i*7 + j
// ---------------------------------------------------------------------------
__global__ __launch_bounds__(256) void roi_pool_kernel(const float* __restrict__ feat,
                                                       const int* __restrict__ roi_out,
                                                       float* __restrict__ pooled) {
    int idx = blockIdx.x * 256 + threadIdx.x;
    if (idx >= NKEEP * D1) return;
    int r    = idx / D1;
    int rem  = idx - r * D1;
    int c    = rem / 49;
    int cell = rem - c * 49;
    int i = cell / 7;
    int j = cell - i * 7;
    int x = roi_out[r*4+0], y = roi_out[r*4+1], w = roi_out[r*4+2], h = roi_out[r*4+3];
    int r0 = y + (i * h) / 7;
    int r1 = y + ((i + 1) * h + 6) / 7;
    int c0 = x + (j * w) / 7;
    int c1 = x + ((j + 1) * w + 6) / 7;
    const float* fc = feat + (size_t)c * (FH * FWW);
    float m = -INFINITY;
    for (int rr = r0; rr < r1; ++rr) {
        const float* fr = fc + rr * FWW;
        for (int cc2 = c0; cc2 < c1; ++cc2) m = fmaxf(m, fr[cc2]);
    }
    pooled[idx] = m;
}

// ---------------------------------------------------------------------------
// Kernel 3: o[n][k] = b[k]  (bias init; fc1 atomically accumulates on top)
// ---------------------------------------------------------------------------
__global__ __launch_bounds__(256) void init_bias8_kernel(const float* __restrict__ b,
                                                         float* __restrict__ o, int K) {
    int i = blockIdx.x * 256 + threadIdx.x;
    if (i < NKEEP * K) o[i] = b[i & (K - 1)];
}

// ---------------------------------------------------------------------------
// Kernel 4: FC1 — R1 structure + 1-deep register prefetch of the w-loads.
// Per iter: issue f (L2, fast) FIRST, then next iter's w (HBM) — the FMA
// wait then only drains f + the w issued one full iteration ago (~1000cy
// of cover) instead of this iteration's w (full 900cy exposed).
// ---------------------------------------------------------------------------
__global__ __launch_bounds__(256) void fc1_kernel(const float* __restrict__ w1,
                                                  const float* __restrict__ flat,
                                                  float* __restrict__ o1) {
    const int kb = blockIdx.x >> 4;       // 0..63
    const int ds = blockIdx.x & 15;       // 0..15
    const int tid = threadIdx.x;
    const int kq = tid >> 4;              // 0..15
    const int dl = tid & 15;              // 0..15
    const int k0 = kb * 64 + kq * 4;
    const int dbase = ds * DPS + dl * 4;

    const float* wp = w1 + (size_t)k0 * D1 + dbase;
    const float* fp = flat + dbase;

    float acc[4][8];
    #pragma unroll
    for (int a = 0; a < 4; ++a)
        #pragma unroll
        for (int n = 0; n < 8; ++n) acc[a][n] = 0.f;

    // preload iter-0 w
    v4 wa[4];
    #pragma unroll
    for (int a = 0; a < 4; ++a) wa[a] = *(const v4*)(wp + (size_t)a * D1);

    for (int itn = 0; itn < DPS / 64; ++itn) {   // 98 iters of 64 cols
        const int off  = itn * 64;
        const int offn = (itn < DPS / 64 - 1) ? off + 64 : off;  // dummy last

        // (1) f loads — L2-resident, issued first so the FMA wait is cheap
        v4 fv[8];
        #pragma unroll
        for (int n = 0; n < 8; ++n) fv[n] = *(const v4*)(fp + (size_t)n * D1 + off);

        // (2) prefetch next iteration's w — stays in flight through the FMAs
        v4 wb[4];
        #pragma unroll
        for (int a = 0; a < 4; ++a) wb[a] = *(const v4*)(wp + (size_t)a * D1 + offn);

        // (3) FMA block on the w loaded one iteration ago
        #pragma unroll
        for (int n = 0; n < 8; ++n) {
            acc[0][n] += wa[0][0]*fv[n][0] + wa[0][1]*fv[n][1] + wa[0][2]*fv[n][2] + wa[0][3]*fv[n][3];
            acc[1][n] += wa[1][0]*fv[n][0] + wa[1][1]*fv[n][1] + wa[1][2]*fv[n][2] + wa[1][3]*fv[n][3];
            acc[2][n] += wa[2][0]*fv[n][0] + wa[2][1]*fv[n][1] + wa[2][2]*fv[n][2] + wa[2][3]*fv[n][3];
            acc[3][n] += wa[3][0]*fv[n][0] + wa[3][1]*fv[n][1] + wa[3][2]*fv[n][2] + wa[3][3]*fv[n][3];
        }

        #pragma unroll
        for (int a = 0; a < 4; ++a) wa[a] = wb[a];
    }

    // reduce across the 16 d-lanes, then atomic into o1
    #pragma unroll
    for (int a = 0; a < 4; ++a) {
        #pragma unroll
        for (int n = 0; n < 8; ++n) {
            float v = acc[a][n];
            v += __shfl_xor(v, 1);
            v += __shfl_xor(v, 2);
            v += __shfl_xor(v, 4);
            v += __shfl_xor(v, 8);
            if (dl == 0) atomicAdd(&o1[n * K1 + k0 + a], v);
        }
    }
}

// ---------------------------------------------------------------------------
// Kernel 5: FC2 (8x4096)@(4096x4096). One wave per output row k.
// ---------------------------------------------------------------------------
__global__ __launch_bounds__(256) void fc2_kernel(const float* __restrict__ w2,
                                                  const float* __restrict__ o1,
                                                  const float* __restrict__ b2,
                                                  float* __restrict__ o2) {
    int gw   = (blockIdx.x * 256 + threadIdx.x) >> 6;
    int lane = threadIdx.x & 63;
    if (gw >= K1) return;
    const float4* wr = (const float4*)(w2 + (size_t)gw * K1);
    const float4* fo = (const float4*)o1;
    float acc[8];
    #pragma unroll
    for (int n = 0; n < 8; ++n) acc[n] = 0.f;
    for (int itn = 0; itn < K1 / 256; ++itn) {   // 16
        float4 wv = wr[itn * 64 + lane];
        #pragma unroll
        for (int n = 0; n < 8; ++n) {
            float4 f = fo[n * (K1/4) + itn * 64 + lane];
            acc[n] += wv.x*f.x + wv.y*f.y + wv.z*f.z + wv.w*f.w;
        }
    }
    #pragma unroll
    for (int n = 0; n < 8; ++n) {
        float v = acc[n];
        #pragma unroll
        for (int m = 32; m >= 1; m >>= 1) v += __shfl_xor(v, m);
        if (lane == 0) o2[n * K1 + gw] = v + b2[gw];
    }
}

// ---------------------------------------------------------------------------
// Kernel 6: heads. k<81 -> wc/bc, else wl/bl. out (8,405) row-major.
// ---------------------------------------------------------------------------
__global__ __launch_bounds__(256) void fc3_kernel(const float* __restrict__ wc,
                                                  const float* __restrict__ bc,
                                                  const float* __restrict__ wl,
                                                  const float* __restrict__ bl,
                                                  const float* __restrict__ o2,
                                                  float* __restrict__ out) {
    int gw   = (blockIdx.x * 256 + threadIdx.x) >> 6;
    int lane = threadIdx.x & 63;
    if (gw >= 405) return;
    const float* wrow; float bias;
    if (gw < 81) { wrow = wc + (size_t)gw * K1;        bias = bc[gw]; }
    else         { wrow = wl + (size_t)(gw - 81) * K1; bias = bl[gw - 81]; }
    const float4* wr = (const float4*)wrow;
    const float4* fo = (const float4*)o2;
    float acc[8];
    #pragma unroll
    for (int n = 0; n < 8; ++n) acc[n] = 0.f;
    for (int itn = 0; itn < K1 / 256; ++itn) {
        float4 wv = wr[itn * 64 + lane];
        #pragma unroll
        for (int n = 0; n < 8; ++n) {
            float4 f = fo[n * (K1/4) + itn * 64 + lane];
            acc[n] += wv.x*f.x + wv.y*f.y + wv.z*f.z + wv.w*f.w;
        }
    }
    #pragma unroll
    for (int n = 0; n < 8; ++n) {
        float v = acc[n];
        #pragma unroll
        for (int m = 32; m >= 1; m >>= 1) v += __shfl_xor(v, m);
        if (lane == 0) out[n * 405 + gw] = v + bias;
    }
}

// ---------------------------------------------------------------------------
extern "C" void kernel_launch(void* const* d_in, const int* in_sizes, int n_in,
                              void* d_out, int out_size, void* d_ws, size_t ws_size,
                              hipStream_t stream) {
    const float* feat   = (const float*)d_in[0];
    const float* rois   = (const float*)d_in[1];
    const float* scores = (const float*)d_in[2];
    const float* w1     = (const float*)d_in[3];
    const float* b1     = (const float*)d_in[4];
    const float* w2     = (const float*)d_in[5];
    const float* b2     = (const float*)d_in[6];
    const float* wc     = (const float*)d_in[7];
    const float* bc     = (const float*)d_in[8];
    const float* wl     = (const float*)d_in[9];
    const float* bl     = (const float*)d_in[10];
    float* out = (float*)d_out;

    // workspace layout (floats): [0..255] roi ints, then pooled, o1, o2
    int*   roi_out = (int*)d_ws;
    float* pooled  = (float*)d_ws + 256;
    float* o1      = pooled + (size_t)NKEEP * D1;
    float* o2      = o1 + NKEEP * K1;

    nms_sel_kernel<<<1, 256, 0, stream>>>(rois, scores, roi_out);
    roi_pool_kernel<<<(NKEEP * D1 + 255) / 256, 256, 0, stream>>>(feat, roi_out, pooled);
    init_bias8_kernel<<<(NKEEP * K1 + 255) / 256, 256, 0, stream>>>(b1, o1, K1);
    fc1_kernel<<<64 * NSLICE, 256, 0, stream>>>(w1, pooled, o1);
    fc2_kernel<<<K1 / 4, 256, 0, stream>>>(w2, o1, b2, o2);
    fc3_kernel<<<(405 * 64 + 255) / 256, 256, 0, stream>>>(wc, bc, wl, bl, o2, out);
}